// Round 3
// baseline (247.652 us; speedup 1.0000x reference)
//
#include <hip/hip_runtime.h>
#include <hip/hip_bf16.h>

using bf16 = __hip_bfloat16;
typedef __attribute__((ext_vector_type(8))) short bf16x8;
typedef __attribute__((ext_vector_type(4))) float f32x4;
typedef __attribute__((address_space(3))) const char lds_cc;

#define DECAY 0.25f

// ---------------------------------------------------------------- helpers
__device__ __forceinline__ void gload_lds16(const void* g, void* l) {
  __builtin_amdgcn_global_load_lds(
      (const __attribute__((address_space(1))) void*)g,
      (__attribute__((address_space(3))) void*)l, 16, 0, 0);
}

__device__ __forceinline__ bf16x8 dsr128(const char* p) {
  bf16x8 r;
  asm volatile("ds_read_b128 %0, %1" : "=v"(r) : "v"((lds_cc*)p));
  return r;
}

#define SBAR()                                  \
  do {                                          \
    __builtin_amdgcn_sched_barrier(0);          \
    __builtin_amdgcn_s_barrier();               \
    __builtin_amdgcn_sched_barrier(0);          \
  } while (0)

#define VMCNT4() asm volatile("s_waitcnt vmcnt(4)" ::: "memory")
#define LGKM0()                                   \
  do {                                            \
    asm volatile("s_waitcnt lgkmcnt(0)" ::: "memory"); \
    __builtin_amdgcn_sched_barrier(0);            \
  } while (0)

__device__ __forceinline__ unsigned short f2bf(float f) {
  __hip_bfloat16 h = __float2bfloat16(f);
  return *reinterpret_cast<unsigned short*>(&h);
}

// ---------------------------------------------------------------- prep kernels
__global__ void cast_x_k(const float4* __restrict__ x, ushort4* __restrict__ xb, int n4) {
  int i = blockIdx.x * blockDim.x + threadIdx.x;
  int stride = gridDim.x * blockDim.x;
  for (; i < n4; i += stride) {
    float4 v = x[i];
    ushort4 o;
    o.x = f2bf(v.x); o.y = f2bf(v.y); o.z = f2bf(v.z); o.w = f2bf(v.w);
    xb[i] = o;
  }
}

__global__ void transpose_cast_k(const float* __restrict__ w, bf16* __restrict__ wt, int N) {
  __shared__ float t[32][33];
  int bx = blockIdx.x * 32, by = blockIdx.y * 32;
  int tx = threadIdx.x, ty = threadIdx.y;  // block (32,8)
#pragma unroll
  for (int i = 0; i < 32; i += 8)
    t[ty + i][tx] = w[(size_t)(by + ty + i) * N + bx + tx];
  __syncthreads();
#pragma unroll
  for (int i = 0; i < 32; i += 8)
    wt[(size_t)(bx + ty + i) * N + by + tx] = __float2bfloat16(t[tx][ty + i]);
}

// ---------------------------------------------------------------- 256x256 pipelined GEMM
// C[M][N] = A[M][K] * BT[N][K]^T (+bias, optional residual epilogue)
// LDS per buffer (64KB): A_kl@0, A_kr@16384, B_kl@32768, B_kr@49152. 2 buffers.
//
// FRAGMENT-MAJOR plane layout (conflict-free): a 16KB plane holds 16 frags of
// 1024B; byte d = f*1024 + l*16 holds src[row0 + f*16 + (l&15)][k0 + (l>>4)*8 ..+8].
// Read side: MFMA frag g is ds_read_b128 at g*1024 + lane*16 -> lane i reads
// base+i*16, a contiguous 1024B block: zero bank conflicts. LDS dest stays
// linear per-wave (gload_lds constraint); permutation lives in the global src.

__device__ __forceinline__ void stage_plane(const bf16* __restrict__ src, int ldk,
                                            int row0, int k0, char* plane, int tid) {
#pragma unroll
  for (int u = 0; u < 2; ++u) {
    int d = tid * 16 + u * 8192;
    int f = d >> 10;
    int l = (d >> 4) & 63;
    const bf16* g = src + (size_t)(row0 + f * 16 + (l & 15)) * ldk + k0 + (l >> 4) * 8;
    gload_lds16(g, plane + d);
  }
}

__device__ __forceinline__ void ld4(const char* base, int ro, bf16x8 (&v)[4]) {
#pragma unroll
  for (int i = 0; i < 4; ++i) v[i] = dsr128(base + i * 1024 + ro);
}

template <int MH>
__device__ __forceinline__ void mfma16(const bf16x8 (&a)[4], const bf16x8 (&b)[4],
                                       f32x4 (&acc)[8][4]) {
#pragma unroll
  for (int i = 0; i < 4; ++i)
#pragma unroll
    for (int j = 0; j < 4; ++j)
      acc[MH * 4 + i][j] =
          __builtin_amdgcn_mfma_f32_16x16x32_bf16(a[i], b[j], acc[MH * 4 + i][j], 0, 0, 0);
}

template <int EPI>
__global__ __launch_bounds__(512, 2) void gemm256_k(
    const bf16* __restrict__ A, const bf16* __restrict__ BT,
    float* __restrict__ C, const float* __restrict__ bias,
    const float* __restrict__ xres, const float* __restrict__ alpha_p,
    int M, int N, int K) {
  __shared__ char lds[131072];
  const int tid = threadIdx.x;
  const int lane = tid & 63;
  const int w = tid >> 6;
  const int wr = w >> 2, wc = w & 3;      // 2M x 4N waves
  const int tm = blockIdx.x * 256, tn = blockIdx.y * 256;
  const int ro = lane * 16;               // conflict-free frag read offset
  const int NT = K >> 6;

  f32x4 acc[8][4] = {};

  // prologue: tile0 all planes + tile1 kl planes
  stage_plane(A,  K, tm, 0,  lds + 0,     tid);
  stage_plane(BT, K, tn, 0,  lds + 32768, tid);
  stage_plane(A,  K, tm, 32, lds + 16384, tid);
  stage_plane(BT, K, tn, 32, lds + 49152, tid);
  stage_plane(A,  K, tm, 64, lds + 65536 + 0,     tid);
  stage_plane(BT, K, tn, 64, lds + 65536 + 32768, tid);
  VMCNT4();
  SBAR();

  for (int t = 0; t < NT; ++t) {
    const char* cb = lds + (t & 1) * 65536;        // compute buffer
    char* nb  = lds + ((t + 1) & 1) * 65536;       // next buffer (stage kr of t+1)
    char* cbw = lds + (t & 1) * 65536;             // current buffer (stage kl of t+2)
    const int k1 = (t + 1 < NT ? t + 1 : NT - 1) * 64;
    const int k2 = (t + 2 < NT ? t + 2 : NT - 1) * 64;
    bf16x8 a[4], b[4];

    // ---- p0: (kh=0, mh=0); stage A_kr(t+1)
    ld4(cb + wr * 8192, ro, a);
    ld4(cb + 32768 + wc * 4096, ro, b);
    stage_plane(A, K, tm, k1 + 32, nb + 16384, tid);
    SBAR();
    LGKM0();
    __builtin_amdgcn_s_setprio(1);
    mfma16<0>(a, b, acc);
    __builtin_amdgcn_s_setprio(0);
    SBAR();

    // ---- p1: (kh=0, mh=1); stage B_kr(t+1)
    ld4(cb + wr * 8192 + 4096, ro, a);
    stage_plane(BT, K, tn, k1 + 32, nb + 49152, tid);
    SBAR();
    LGKM0();
    __builtin_amdgcn_s_setprio(1);
    mfma16<1>(a, b, acc);
    __builtin_amdgcn_s_setprio(0);
    __builtin_amdgcn_sched_barrier(0);
    VMCNT4();                       // kr(t) landed (needed p2/p3); kr(t+1) in flight
    SBAR();

    // ---- p2: (kh=1, mh=0); stage A_kl(t+2)
    ld4(cb + 16384 + wr * 8192, ro, a);
    ld4(cb + 32768 + 16384 + wc * 4096, ro, b);
    stage_plane(A, K, tm, k2, cbw + 0, tid);
    SBAR();
    LGKM0();
    __builtin_amdgcn_s_setprio(1);
    mfma16<0>(a, b, acc);
    __builtin_amdgcn_s_setprio(0);
    SBAR();

    // ---- p3: (kh=1, mh=1); stage B_kl(t+2)
    ld4(cb + 16384 + wr * 8192 + 4096, ro, a);
    stage_plane(BT, K, tn, k2, cbw + 32768, tid);
    SBAR();
    LGKM0();
    __builtin_amdgcn_s_setprio(1);
    mfma16<1>(a, b, acc);
    __builtin_amdgcn_s_setprio(0);
    __builtin_amdgcn_sched_barrier(0);
    VMCNT4();                       // kl(t+1) landed (needed next p0); kl(t+2) in flight
    SBAR();
  }

  // epilogue: C/D layout col=lane&15, row=(lane>>4)*4+r  [m89]
  float alpha = 0.f;
  if constexpr (EPI) alpha = *alpha_p;
#pragma unroll
  for (int i = 0; i < 8; ++i) {
    int m0 = tm + wr * 128 + i * 16 + (lane >> 4) * 4;
#pragma unroll
    for (int j = 0; j < 4; ++j) {
      int n = tn + wc * 64 + j * 16 + (lane & 15);
      float bb = bias[n];
#pragma unroll
      for (int r = 0; r < 4; ++r) {
        size_t idx = (size_t)(m0 + r) * N + n;
        float v = acc[i][j][r] + bb;
        if constexpr (EPI) v = xres[idx] + alpha * v;
        C[idx] = v;
      }
    }
  }
}

// ---------------------------------------------------------------- chunked LIF scan
__global__ void snn_scan_k(const float* __restrict__ xp, bf16* __restrict__ sp,
                           const float* __restrict__ thre_p,
                           int T, int H, int CHUNK, int WARM) {
  int h = blockIdx.x * blockDim.x + threadIdx.x;
  int b = blockIdx.y;
  int c = blockIdx.z;
  float thre = *thre_p;
  float l1 = thre, l2 = 2.f * thre, l3 = 3.f * thre, l4 = 4.f * thre;
  int t0 = c * CHUNK;
  int tw = t0 - WARM;
  if (tw < 0) tw = 0;
  const float* xcol = xp + (size_t)b * T * H + h;
  bf16* scol = sp + (size_t)b * T * H + h;
  float mem = 0.f;
  for (int t = tw; t < t0; ++t) {  // warmup (state error ~0.25^WARM)
    float xv = xcol[(size_t)t * H];
    mem = DECAY * mem + xv;
    float s = (float)((mem >= l1) + (mem >= l2) + (mem >= l3) + (mem >= l4));
    mem -= s * thre;
  }
  for (int t = t0; t < t0 + CHUNK; ++t) {
    float xv = xcol[(size_t)t * H];
    mem = DECAY * mem + xv;
    float s = (float)((mem >= l1) + (mem >= l2) + (mem >= l3) + (mem >= l4));
    mem -= s * thre;
    scol[(size_t)t * H] = __float2bfloat16(s);  // 0..4 exact in bf16
  }
}

// ---------------------------------------------------------------- launch
extern "C" void kernel_launch(void* const* d_in, const int* in_sizes, int n_in,
                              void* d_out, int out_size, void* d_ws, size_t ws_size,
                              hipStream_t stream) {
  const float* x     = (const float*)d_in[0];
  const float* alpha = (const float*)d_in[1];
  const float* thre  = (const float*)d_in[2];
  const float* w_in  = (const float*)d_in[3];
  const float* b_in  = (const float*)d_in[4];
  const float* w_out = (const float*)d_in[5];
  const float* b_out = (const float*)d_in[6];
  float* out = (float*)d_out;

  const int B = 4, T = 2048, H = 2048;
  const int M = B * T;  // 8192
  const int K = H, N = H;

  char* ws = (char*)d_ws;
  bf16* xb     = (bf16*)(ws);
  bf16* spikes = (bf16*)(ws);  // alias: xb dead after GEMM1
  bf16* w_inT  = (bf16*)(ws + (size_t)M * K * 2);
  bf16* w_outT = (bf16*)(ws + (size_t)M * K * 2 + (size_t)K * N * 2);
  float* xp    = (float*)(ws + (size_t)M * K * 2 + (size_t)2 * K * N * 2);

  cast_x_k<<<2048, 256, 0, stream>>>((const float4*)x, (ushort4*)xb, M * K / 4);
  dim3 tb(32, 8);
  dim3 tg(N / 32, K / 32);
  transpose_cast_k<<<tg, tb, 0, stream>>>(w_in, w_inT, N);
  transpose_cast_k<<<tg, tb, 0, stream>>>(w_out, w_outT, N);

  dim3 gg(M / 256, N / 256);
  gemm256_k<0><<<gg, 512, 0, stream>>>(xb, w_inT, xp, b_in, nullptr, nullptr, M, N, K);

  const int CHUNK = 128, WARM = 32, NC = T / CHUNK;
  dim3 sg(H / 256, B, NC);
  snn_scan_k<<<sg, 256, 0, stream>>>(xp, spikes, thre, T, H, CHUNK, WARM);

  gemm256_k<1><<<gg, 512, 0, stream>>>(spikes, w_outT, out, b_out, x, alpha, M, N, K);
}

// Round 4
// 234.317 us; speedup vs baseline: 1.0569x; 1.0569x over previous
//
#include <hip/hip_runtime.h>
#include <hip/hip_bf16.h>

using bf16 = __hip_bfloat16;
typedef __attribute__((ext_vector_type(8))) short bf16x8;
typedef __attribute__((ext_vector_type(4))) float f32x4;

#define DECAY 0.25f

// ---------------------------------------------------------------- helpers
__device__ __forceinline__ void gload_lds16(const void* g, void* l) {
  __builtin_amdgcn_global_load_lds(
      (const __attribute__((address_space(1))) void*)g,
      (__attribute__((address_space(3))) void*)l, 16, 0, 0);
}

// phase fence: no loads/MFMA cross; counted vmcnt keeps 8 stage-loads in flight
#define PHASE_END()                                        \
  do {                                                     \
    __builtin_amdgcn_sched_barrier(0);                     \
    asm volatile("s_waitcnt vmcnt(8)" ::: "memory");       \
    __builtin_amdgcn_s_barrier();                          \
    __builtin_amdgcn_sched_barrier(0);                     \
  } while (0)

__device__ __forceinline__ unsigned short f2bf(float f) {
  __hip_bfloat16 h = __float2bfloat16(f);
  return *reinterpret_cast<unsigned short*>(&h);
}

// ---------------------------------------------------------------- prep kernels
__global__ void cast_x_k(const float4* __restrict__ x, ushort4* __restrict__ xb, int n4) {
  int i = blockIdx.x * blockDim.x + threadIdx.x;
  int stride = gridDim.x * blockDim.x;
  for (; i < n4; i += stride) {
    float4 v = x[i];
    ushort4 o;
    o.x = f2bf(v.x); o.y = f2bf(v.y); o.z = f2bf(v.z); o.w = f2bf(v.w);
    xb[i] = o;
  }
}

__global__ void transpose_cast_k(const float* __restrict__ w, bf16* __restrict__ wt, int N) {
  __shared__ float t[32][33];
  int bx = blockIdx.x * 32, by = blockIdx.y * 32;
  int tx = threadIdx.x, ty = threadIdx.y;  // block (32,8)
#pragma unroll
  for (int i = 0; i < 32; i += 8)
    t[ty + i][tx] = w[(size_t)(by + ty + i) * N + bx + tx];
  __syncthreads();
#pragma unroll
  for (int i = 0; i < 32; i += 8)
    wt[(size_t)(bx + ty + i) * N + by + tx] = __float2bfloat16(t[tx][ty + i]);
}

// ---------------------------------------------------------------- 256x256 pipelined GEMM
// C[M][N] = A[M][K] * BT[N][K]^T (+bias; EPI=1 residual; OutT = float|bf16)
// LDS per buffer (64KB): A_kl@0, A_kr@16384, B_kl@32768, B_kr@49152. 2 buffers.
// FRAGMENT-MAJOR planes (conflict-free, verified 0 conflicts in R3):
//   plane byte d = f*1024 + l*16  holds  src[row0+f*16+(l&15)][k0+(l>>4)*8 ..+8]
// 2 phases/tile (one per kh-half), 1 barrier/phase, compiler-scheduled lgkmcnt,
// vmcnt(8) counted at phase end (2 plane-pairs always in flight).

__device__ __forceinline__ void stage_plane(const bf16* __restrict__ src, int ldk,
                                            int row0, int k0, char* plane, int tid) {
#pragma unroll
  for (int u = 0; u < 2; ++u) {
    int d = tid * 16 + u * 8192;
    int f = d >> 10;
    int l = (d >> 4) & 63;
    const bf16* g = src + (size_t)(row0 + f * 16 + (l & 15)) * ldk + k0 + (l >> 4) * 8;
    gload_lds16(g, plane + d);
  }
}

__device__ __forceinline__ void mfma16(const bf16x8 (&a)[4], const bf16x8 (&b)[4],
                                       f32x4 (&acc)[8][4], int mh) {
#pragma unroll
  for (int i = 0; i < 4; ++i)
#pragma unroll
    for (int j = 0; j < 4; ++j)
      acc[mh * 4 + i][j] =
          __builtin_amdgcn_mfma_f32_16x16x32_bf16(a[i], b[j], acc[mh * 4 + i][j], 0, 0, 0);
}

template <int EPI, typename OutT>
__global__ __launch_bounds__(512, 2) void gemm256_k(
    const bf16* __restrict__ A, const bf16* __restrict__ BT,
    OutT* __restrict__ C, const float* __restrict__ bias,
    const float* __restrict__ xres, const float* __restrict__ alpha_p,
    int M, int N, int K) {
  __shared__ char lds[131072];
  const int tid = threadIdx.x;
  const int lane = tid & 63;
  const int w = tid >> 6;
  const int wr = w >> 2, wc = w & 3;  // 2M x 4N waves, per-wave 128x64 out
  const int tm = blockIdx.x * 256, tn = blockIdx.y * 256;
  const int ro = lane * 16;
  const int NT = K >> 6;

  f32x4 acc[8][4] = {};

  // prologue: kl(0), kr(0), kl(1) staged (12 loads); wait kl(0) (8 left in flight)
  stage_plane(A,  K, tm, 0,  lds + 0,     tid);
  stage_plane(BT, K, tn, 0,  lds + 32768, tid);
  stage_plane(A,  K, tm, 32, lds + 16384, tid);
  stage_plane(BT, K, tn, 32, lds + 49152, tid);
  stage_plane(A,  K, tm, 64, lds + 65536 + 0,     tid);
  stage_plane(BT, K, tn, 64, lds + 65536 + 32768, tid);
  PHASE_END();

  for (int t = 0; t < NT; ++t) {
    char* cb = lds + (t & 1) * 65536;
    char* nb = lds + ((t + 1) & 1) * 65536;
    const int k1 = (t + 1 < NT ? t + 1 : NT - 1) * 64;  // kr(t+1) k-base-32
    const int k2 = (t + 2 < NT ? t + 2 : NT - 1) * 64;  // kl(t+2) k-base
    bf16x8 a0[4], a1[4], b0[4];

    // ---- phase 0 (kh=0: kl regions); stage kr(t+1) into nb
    {
      const char* pa = cb + wr * 8192;
      const char* pb = cb + 32768 + wc * 4096;
      stage_plane(A,  K, tm, k1 + 32, nb + 16384, tid);
      stage_plane(BT, K, tn, k1 + 32, nb + 49152, tid);
#pragma unroll
      for (int i = 0; i < 4; ++i) a0[i] = *(const bf16x8*)(pa + i * 1024 + ro);
#pragma unroll
      for (int i = 0; i < 4; ++i) b0[i] = *(const bf16x8*)(pb + i * 1024 + ro);
#pragma unroll
      for (int i = 0; i < 4; ++i) a1[i] = *(const bf16x8*)(pa + 4096 + i * 1024 + ro);
      __builtin_amdgcn_s_setprio(1);
      mfma16(a0, b0, acc, 0);
      mfma16(a1, b0, acc, 1);
      __builtin_amdgcn_s_setprio(0);
      PHASE_END();  // vmcnt(8): kr(t) landed (needed next phase)
    }

    // ---- phase 1 (kh=1: kr regions); stage kl(t+2) into cb
    {
      const char* pa = cb + 16384 + wr * 8192;
      const char* pb = cb + 49152 + wc * 4096;
      stage_plane(A,  K, tm, k2, cb + 0,     tid);
      stage_plane(BT, K, tn, k2, cb + 32768, tid);
#pragma unroll
      for (int i = 0; i < 4; ++i) a0[i] = *(const bf16x8*)(pa + i * 1024 + ro);
#pragma unroll
      for (int i = 0; i < 4; ++i) b0[i] = *(const bf16x8*)(pb + i * 1024 + ro);
#pragma unroll
      for (int i = 0; i < 4; ++i) a1[i] = *(const bf16x8*)(pa + 4096 + i * 1024 + ro);
      __builtin_amdgcn_s_setprio(1);
      mfma16(a0, b0, acc, 0);
      mfma16(a1, b0, acc, 1);
      __builtin_amdgcn_s_setprio(0);
      PHASE_END();  // vmcnt(8): kl(t+1) landed (needed next tile p0)
    }
  }

  // epilogue: C/D layout col=lane&15, row=(lane>>4)*4+r  [m89]
  float alpha = 0.f;
  if constexpr (EPI) alpha = *alpha_p;
#pragma unroll
  for (int i = 0; i < 8; ++i) {
    int m0 = tm + wr * 128 + i * 16 + (lane >> 4) * 4;
#pragma unroll
    for (int j = 0; j < 4; ++j) {
      int n = tn + wc * 64 + j * 16 + (lane & 15);
      float bb = bias[n];
#pragma unroll
      for (int r = 0; r < 4; ++r) {
        size_t idx = (size_t)(m0 + r) * N + n;
        float v = acc[i][j][r] + bb;
        if constexpr (EPI) v = xres[idx] + alpha * v;
        if constexpr (__is_same(OutT, bf16)) C[idx] = __float2bfloat16(v);
        else                                 C[idx] = v;
      }
    }
  }
}

// ---------------------------------------------------------------- chunked LIF scan (bf16 in)
__global__ void snn_scan_k(const bf16* __restrict__ xp, bf16* __restrict__ sp,
                           const float* __restrict__ thre_p,
                           int T, int H, int CHUNK, int WARM) {
  int h = blockIdx.x * blockDim.x + threadIdx.x;
  int b = blockIdx.y;
  int c = blockIdx.z;
  float thre = *thre_p;
  float l1 = thre, l2 = 2.f * thre, l3 = 3.f * thre, l4 = 4.f * thre;
  int t0 = c * CHUNK;
  int tw = t0 - WARM;
  if (tw < 0) tw = 0;
  const bf16* xcol = xp + (size_t)b * T * H + h;
  bf16* scol = sp + (size_t)b * T * H + h;
  float mem = 0.f;
  for (int t = tw; t < t0; ++t) {  // warmup (state error ~0.25^WARM)
    float xv = __bfloat162float(xcol[(size_t)t * H]);
    mem = DECAY * mem + xv;
    float s = (float)((mem >= l1) + (mem >= l2) + (mem >= l3) + (mem >= l4));
    mem -= s * thre;
  }
  for (int t = t0; t < t0 + CHUNK; ++t) {
    float xv = __bfloat162float(xcol[(size_t)t * H]);
    mem = DECAY * mem + xv;
    float s = (float)((mem >= l1) + (mem >= l2) + (mem >= l3) + (mem >= l4));
    mem -= s * thre;
    scol[(size_t)t * H] = __float2bfloat16(s);  // 0..4 exact in bf16
  }
}

// ---------------------------------------------------------------- launch
extern "C" void kernel_launch(void* const* d_in, const int* in_sizes, int n_in,
                              void* d_out, int out_size, void* d_ws, size_t ws_size,
                              hipStream_t stream) {
  const float* x     = (const float*)d_in[0];
  const float* alpha = (const float*)d_in[1];
  const float* thre  = (const float*)d_in[2];
  const float* w_in  = (const float*)d_in[3];
  const float* b_in  = (const float*)d_in[4];
  const float* w_out = (const float*)d_in[5];
  const float* b_out = (const float*)d_in[6];
  float* out = (float*)d_out;

  const int B = 4, T = 2048, H = 2048;
  const int M = B * T;  // 8192
  const int K = H, N = H;

  char* ws = (char*)d_ws;
  bf16* xb     = (bf16*)(ws);
  bf16* spikes = (bf16*)(ws);  // alias: xb dead after GEMM1
  bf16* w_inT  = (bf16*)(ws + (size_t)M * K * 2);
  bf16* w_outT = (bf16*)(ws + (size_t)M * K * 2 + (size_t)K * N * 2);
  bf16* xp     = (bf16*)(ws + (size_t)M * K * 2 + (size_t)2 * K * N * 2);

  cast_x_k<<<2048, 256, 0, stream>>>((const float4*)x, (ushort4*)xb, M * K / 4);
  dim3 tb(32, 8);
  dim3 tg(N / 32, K / 32);
  transpose_cast_k<<<tg, tb, 0, stream>>>(w_in, w_inT, N);
  transpose_cast_k<<<tg, tb, 0, stream>>>(w_out, w_outT, N);

  dim3 gg(M / 256, N / 256);
  gemm256_k<0, bf16><<<gg, 512, 0, stream>>>(xb, w_inT, xp, b_in, nullptr, nullptr, M, N, K);

  const int CHUNK = 128, WARM = 32, NC = T / CHUNK;
  dim3 sg(H / 256, B, NC);
  snn_scan_k<<<sg, 256, 0, stream>>>(xp, spikes, thre, T, H, CHUNK, WARM);

  gemm256_k<1, float><<<gg, 512, 0, stream>>>(spikes, w_outT, out, b_out, x, alpha, M, N, K);
}